// Round 15
// baseline (206.987 us; speedup 1.0000x reference)
//
#include <hip/hip_runtime.h>
#include <hip/hip_bf16.h>
#include <math.h>

#define NTOT  8192
#define DIM   512
#define BATCH (NTOT/2)
#define TEMP_INV 5.0f   // 1/0.2
#define GCH   32                      // gram K-chunks (256 samples each)
#define TT2   32                      // 8192 / 256 tiles per side
#define NBLK2 (TT2*(TT2+1)/2)         // 528 upper-triangle 256x256 tiles

typedef __attribute__((ext_vector_type(8))) short bf16x8;
typedef __attribute__((ext_vector_type(4))) float f32x4;

__device__ __forceinline__ float b2f(unsigned short u)
{
    unsigned int x = (unsigned int)u << 16;
    float f; __builtin_memcpy(&f, &x, 4); return f;
}

// column-major triangle decode: t = bj*(bj+1)/2 + bi, bi <= bj.
__device__ __forceinline__ void decode_tile(int t, int& bi, int& bj)
{
    int b = (int)((sqrtf(8.0f * (float)t + 1.0f) - 1.0f) * 0.5f);
    while ((b + 1) * (b + 2) / 2 <= t) ++b;
    while (b * (b + 1) / 2 > t)       --b;
    bj = b;
    bi = t - b * (b + 1) / 2;
}

__device__ __forceinline__ unsigned int pack_bf16_2(float a, float b)
{
    __hip_bfloat16 ha = __float2bfloat16(a), hb = __float2bfloat16(b);
    unsigned short ua, ub;
    __builtin_memcpy(&ua, &ha, 2); __builtin_memcpy(&ub, &hb, 2);
    return (unsigned int)ua | ((unsigned int)ub << 16);
}

// ---------------- normalize: one wave per row ----------------
__global__ __launch_bounds__(256)
void normalize_k(const float* __restrict__ z, __hip_bfloat16* __restrict__ zn)
{
    const int lane = threadIdx.x & 63, wave = threadIdx.x >> 6;
    const int row  = blockIdx.x * 4 + wave;
    const float4* zr = (const float4*)(z + (size_t)row * DIM);
    const float4 a = zr[lane];
    const float4 b = zr[lane + 64];
    float ss = a.x*a.x + a.y*a.y + a.z*a.z + a.w*a.w
             + b.x*b.x + b.y*b.y + b.z*b.z + b.w*b.w;
    #pragma unroll
    for (int off = 1; off < 64; off <<= 1) ss += __shfl_xor(ss, off);
    const float inv = 1.0f / fmaxf(sqrtf(ss), 1e-12f);
    uint2* zo = (uint2*)(zn + (size_t)row * DIM);
    uint2 o0, o1;
    o0.x = pack_bf16_2(a.x * inv, a.y * inv);
    o0.y = pack_bf16_2(a.z * inv, a.w * inv);
    o1.x = pack_bf16_2(b.x * inv, b.y * inv);
    o1.y = pack_bf16_2(b.z * inv, b.w * inv);
    zo[lane]      = o0;
    zo[lane + 64] = o1;
}

// ---------------- transpose zn -> znT [512][8192], fused column sums S ----------------
__global__ __launch_bounds__(256)
void transpose_colsum_k(const __hip_bfloat16* __restrict__ zn,
                        __hip_bfloat16* __restrict__ znT,
                        float* __restrict__ S)
{
    __shared__ unsigned short T[64][72];
    __shared__ float Scol[64];
    const int tid = threadIdx.x;
    const int bs = blockIdx.x & 127;       // sample tile
    const int bd = blockIdx.x >> 7;        // dim tile
    const int s0 = bs * 64, d0 = bd * 64;
    if (tid < 64) Scol[tid] = 0.f;
    const int rr = tid >> 3;
    const int c8 = (tid & 7) * 8;
    float part[8];
    #pragma unroll
    for (int j = 0; j < 8; ++j) part[j] = 0.f;
    #pragma unroll
    for (int h = 0; h < 2; ++h) {
        const int row = rr + h * 32;
        const int Xw = ((row >> 3) & 7) << 3;
        const bf16x8 v = *(const bf16x8*)(zn + (size_t)(s0 + row) * DIM + d0 + c8);
        *(bf16x8*)&T[row][c8 ^ Xw] = v;
        #pragma unroll
        for (int j = 0; j < 8; ++j) part[j] += b2f((unsigned short)v[j]);
    }
    __syncthreads();
    const int Xr = ((c8 >> 3) & 7) << 3;
    #pragma unroll
    for (int h = 0; h < 2; ++h) {
        const int d = rr + h * 32;
        bf16x8 ov;
        #pragma unroll
        for (int j = 0; j < 8; ++j) ov[j] = (short)T[c8 + j][d ^ Xr];
        *(bf16x8*)(znT + (size_t)(d0 + d) * NTOT + s0 + c8) = ov;
    }
    #pragma unroll
    for (int j = 0; j < 8; ++j) atomicAdd(&Scol[c8 + j], part[j]);
    __syncthreads();
    if (tid < 64) atomicAdd(&S[d0 + tid], Scol[tid]);
}

// ---------------- shared MFMA K-loop (aux): 128x128 tile, BK=32, 2-stage ring ----------------
__device__ __forceinline__ void issue4(const __hip_bfloat16* A, int sA,
                                       const __hip_bfloat16* B, int sB,
                                       int gk, unsigned short* Ad, unsigned short* Bd,
                                       int wave, int lane)
{
    const int f_l = lane & 15, q_l = lane >> 4;
    #pragma unroll
    for (int q = 0; q < 2; ++q) {
        const int s = wave * 2 + q;
        const __hip_bfloat16* ga = A + (size_t)(s * 16 + f_l) * sA + gk + q_l * 8;
        const __hip_bfloat16* gb = B + (size_t)(s * 16 + f_l) * sB + gk + q_l * 8;
        __builtin_amdgcn_global_load_lds(
            (const __attribute__((address_space(1))) unsigned int*)ga,
            (__attribute__((address_space(3))) unsigned int*)(Ad + s * 512 + lane * 8),
            16, 0, 0);
        __builtin_amdgcn_global_load_lds(
            (const __attribute__((address_space(1))) unsigned int*)gb,
            (__attribute__((address_space(3))) unsigned int*)(Bd + s * 512 + lane * 8),
            16, 0, 0);
    }
}

template<int NSTEP>
__device__ __forceinline__ void mm_kloop(const __hip_bfloat16* A, int sA,
                                         const __hip_bfloat16* B, int sB,
                                         unsigned short (*As)[4096],
                                         unsigned short (*Bs)[4096],
                                         f32x4 acc[4][4], int wave, int lane)
{
    const int wr = wave >> 1, wc = wave & 1;
    issue4(A, sA, B, sB, 0,  As[0], Bs[0], wave, lane);
    issue4(A, sA, B, sB, 32, As[1], Bs[1], wave, lane);
    #pragma unroll
    for (int ki = 0; ki < NSTEP; ++ki) {
        if (ki < NSTEP - 1) asm volatile("s_waitcnt vmcnt(4)\n\ts_barrier" ::: "memory");
        else                asm volatile("s_waitcnt vmcnt(0)\n\ts_barrier" ::: "memory");
        __builtin_amdgcn_sched_barrier(0);
        const unsigned short* Ap = As[ki & 1];
        const unsigned short* Bp = Bs[ki & 1];
        bf16x8 af[4], bfr[4];
        #pragma unroll
        for (int r = 0; r < 4; ++r)
            af[r] = *(const bf16x8*)(Ap + (wr * 4 + r) * 512 + lane * 8);
        #pragma unroll
        for (int c = 0; c < 4; ++c)
            bfr[c] = *(const bf16x8*)(Bp + (wc * 4 + c) * 512 + lane * 8);
        #pragma unroll
        for (int r = 0; r < 4; ++r)
            #pragma unroll
            for (int c = 0; c < 4; ++c)
                acc[r][c] = __builtin_amdgcn_mfma_f32_16x16x32_bf16(af[r], bfr[c], acc[r][c], 0, 0, 0);
        if (ki + 2 < NSTEP) {
            __builtin_amdgcn_sched_barrier(0);
            asm volatile("s_waitcnt lgkmcnt(0)\n\ts_barrier" ::: "memory");
            __builtin_amdgcn_sched_barrier(0);
            issue4(A, sA, B, sB, (ki + 2) * 32, As[ki & 1], Bs[ki & 1], wave, lane);
        }
    }
}

// ---------------- Gram partials: 16 quadrants x GCH chunks ----------------
__global__ __launch_bounds__(256, 4)
void gram_k(const __hip_bfloat16* __restrict__ znT, float* __restrict__ Gpart)
{
    __shared__ unsigned short As[2][4096];
    __shared__ unsigned short Bs[2][4096];
    const int tid = threadIdx.x, wave = tid >> 6, lane = tid & 63;
    const int f_l = lane & 15, q_l = lane >> 4;
    const int t = blockIdx.x >> 5, ch = blockIdx.x & 31;
    const int di = (t >> 2) * 128, dj = (t & 3) * 128;
    const int wr = wave >> 1, wc = wave & 1;
    f32x4 acc[4][4];
    #pragma unroll
    for (int r = 0; r < 4; ++r)
        #pragma unroll
        for (int c = 0; c < 4; ++c) acc[r][c] = (f32x4){0.f, 0.f, 0.f, 0.f};
    mm_kloop<8>(znT + (size_t)di * NTOT + ch * 256, NTOT,
                znT + (size_t)dj * NTOT + ch * 256, NTOT, As, Bs, acc, wave, lane);
    float* gp = Gpart + ((size_t)t * GCH + ch) * 16384;
    #pragma unroll
    for (int r = 0; r < 4; ++r)
        #pragma unroll
        for (int c = 0; c < 4; ++c)
            #pragma unroll
            for (int u = 0; u < 4; ++u) {
                const int row = wr * 64 + r * 16 + q_l * 4 + u;
                const int col = wc * 64 + c * 16 + f_l;
                gp[row * 128 + col] = acc[r][c][u];
            }
}

// ---------------- reduce GCH partials -> bf16 G ----------------
__global__ __launch_bounds__(256)
void gram_fin_k(const float* __restrict__ Gpart, __hip_bfloat16* __restrict__ G1)
{
    const int t  = blockIdx.x >> 5;
    const int e  = ((blockIdx.x & 31) * 256 + threadIdx.x) * 2;
    const int di = (t >> 2) * 128, dj = (t & 3) * 128;
    const float* qb = Gpart + (size_t)t * GCH * 16384 + e;
    float sx = 0.f, sy = 0.f;
    #pragma unroll
    for (int ch = 0; ch < GCH; ++ch) {
        const float2 v = *(const float2*)(qb + ch * 16384);
        sx += v.x; sy += v.y;
    }
    const int rl = e >> 7, cl = e & 127;
    *(unsigned int*)(G1 + (size_t)(di + rl) * 512 + dj + cl) = pack_bf16_2(sx, sy);
}

// ---------------- rowsumsq partials: 16 per-wave slices (race-free) ----------------
__global__ __launch_bounds__(256, 4)
void rowstats_k(const __hip_bfloat16* __restrict__ zn,
                const __hip_bfloat16* __restrict__ G1,
                float* __restrict__ rsq_part)
{
    __shared__ unsigned short As[2][4096];
    __shared__ unsigned short Bs[2][4096];
    const int tid = threadIdx.x, wave = tid >> 6, lane = tid & 63;
    const int f_l = lane & 15, q_l = lane >> 4;
    const int g  = blockIdx.x >> 3;
    const int R0 = g * 128;
    const int cb = (blockIdx.x >> 1) & 3;
    const int C0 = cb * 128;
    const int khi = blockIdx.x & 1;
    const int kh  = khi * 256;
    const int wr = wave >> 1, wc = wave & 1;
    const int part = ((cb * 2 + khi) << 1) | wc;
    f32x4 acc[4][4];
    #pragma unroll
    for (int r = 0; r < 4; ++r)
        #pragma unroll
        for (int c = 0; c < 4; ++c) acc[r][c] = (f32x4){0.f, 0.f, 0.f, 0.f};
    mm_kloop<8>(zn + (size_t)R0 * DIM + kh, DIM, G1 + (size_t)C0 * DIM + kh, DIM,
                As, Bs, acc, wave, lane);
    #pragma unroll
    for (int r = 0; r < 4; ++r) {
        float4 pv;
        #pragma unroll
        for (int u = 0; u < 4; ++u) {
            const int i = R0 + wr * 64 + r * 16 + q_l * 4 + u;
            float p = 0.f;
            #pragma unroll
            for (int c = 0; c < 4; ++c) {
                const int col = C0 + wc * 64 + c * 16 + f_l;
                unsigned short zb;
                __builtin_memcpy(&zb, zn + (size_t)i * DIM + col, 2);
                p += acc[r][c][u] * b2f(zb);
            }
            p += __shfl_xor(p, 1); p += __shfl_xor(p, 2);
            p += __shfl_xor(p, 4); p += __shfl_xor(p, 8);
            ((float*)&pv)[u] = p;
        }
        if (f_l == 0)
            *(float4*)(rsq_part + (size_t)part * NTOT + R0 + wr * 64 + r * 16 + q_l * 4) = pv;
    }
}

// ---------------- finalize stats + positive pairs ----------------
__global__ __launch_bounds__(256)
void finalize_pos_k(const __hip_bfloat16* __restrict__ zn,
                    const float* __restrict__ S,
                    const float* __restrict__ rsq_part,
                    const int* __restrict__ labels,
                    float* __restrict__ mu_d,
                    float* __restrict__ inv2s2,
                    double* __restrict__ pos_acc)
{
    const int lane = threadIdx.x & 63, wave = threadIdx.x >> 6;
    const int row = blockIdx.x * 4 + wave;
    const bf16x8 v = *(const bf16x8*)(zn + (size_t)row * DIM + lane * 8);
    const float4 sa = *(const float4*)(S + lane * 8);
    const float4 sb = *(const float4*)(S + lane * 8 + 4);
    float acc = b2f((unsigned short)v[0]) * sa.x + b2f((unsigned short)v[1]) * sa.y
              + b2f((unsigned short)v[2]) * sa.z + b2f((unsigned short)v[3]) * sa.w
              + b2f((unsigned short)v[4]) * sb.x + b2f((unsigned short)v[5]) * sb.y
              + b2f((unsigned short)v[6]) * sb.z + b2f((unsigned short)v[7]) * sb.w;
    float vp = 0.f;
    if (row < BATCH) {
        const bf16x8 w = *(const bf16x8*)(zn + (size_t)(row + BATCH) * DIM + lane * 8);
        #pragma unroll
        for (int j = 0; j < 8; ++j)
            vp += b2f((unsigned short)v[j]) * b2f((unsigned short)w[j]);
    }
    #pragma unroll
    for (int off = 1; off < 64; off <<= 1) {
        acc += __shfl_xor(acc, off);
        vp  += __shfl_xor(vp, off);
    }
    if (lane == 0) {
        float sq = 0.f;
        #pragma unroll
        for (int p = 0; p < 16; ++p) sq += rsq_part[(size_t)p * NTOT + row];
        const float s = acc;
        const float mean_sim = s * (1.0f / NTOT);
        const float var = (sq - s * mean_sim) * (1.0f / (NTOT - 1));
        mu_d[row]   = 1.0f - mean_sim;
        inv2s2[row] = 1.0f / (2.0f * var);
        if (row < BATCH && labels[row] == labels[row + BATCH])
            atomicAdd(pos_acc, (double)__expf(vp * TEMP_INV));
    }
}

// ---------------- 8-phase 256x256 triangle GEMM + exp epilogue ----------------
// 512 threads = 8 waves (2x4). Wave tile 128x64: acc[8][4]. BK=64 as 2 ksub of 32.
// Dynamic LDS 128KB: region(stage s, ksub h, ab) of 16KB, seg-16 layout (as aux kernels).
// Schedule per K-tile kt (stage st=kt&1): 4 phases, 2 barriers, counted vmcnt(8):
//   a: issue A of (kt+1)ks1 -> st^1.h1 | ds_read af[0..3],bf[0..3] of st.h0 | 16 MFMA
//   b: issue B of (kt+1)ks1             | ds_read af[4..7] of st.h0         | 16 MFMA
//   B1: vmcnt(8) [guards st.h1 = kt ks1: 8 loads issued after its 4] + barrier
//   c: issue A of (kt+2)ks0 -> st.h0 (freed at B1) | ds_read h1 frags | 16 MFMA
//   d: issue B of (kt+2)ks0             | ds_read af[4..7] of st.h1   | 16 MFMA
//   B2: vmcnt(8) [guards (kt+1)ks0] + barrier.  Tail: kt=6 B2->vmcnt(4); kt=7 B1->vmcnt(0).
__global__ __launch_bounds__(512, 2)
void sim_neg_k(const __hip_bfloat16* __restrict__ zn,
               const int*   __restrict__ labels,
               const float* __restrict__ mu_d,
               const float* __restrict__ inv2s2,
               double* __restrict__ neg_acc)
{
    extern __shared__ unsigned short LDS[];
    const int tid = threadIdx.x, w = tid >> 6, lane = tid & 63;
    const int f_l = lane & 15, q_l = lane >> 4;
    int bi, bj;
    decode_tile(blockIdx.x, bi, bj);
    const int R0 = bi * 256, C0 = bj * 256;
    const int wr = w >> 2, wc = w & 3;
    const __hip_bfloat16* A = zn + (size_t)R0 * DIM;
    const __hip_bfloat16* B = zn + (size_t)C0 * DIM;

    // region base in shorts: ((stage*2 + h)*2 + ab) * 8192
    auto rb = [&](int st, int h, int ab) { return ((st * 2 + h) * 2 + ab) * 8192; };
    auto issue2 = [&](const __hip_bfloat16* src, int gk, int dstbase) {
        #pragma unroll
        for (int q = 0; q < 2; ++q) {
            const int s = w * 2 + q;                     // 16 segs over 8 waves
            const __hip_bfloat16* g = src + (size_t)(s * 16 + f_l) * DIM + gk + q_l * 8;
            __builtin_amdgcn_global_load_lds(
                (const __attribute__((address_space(1))) unsigned int*)g,
                (__attribute__((address_space(3))) unsigned int*)(LDS + dstbase + s * 512 + lane * 8),
                16, 0, 0);
        }
    };

    f32x4 acc[8][4];
    #pragma unroll
    for (int m = 0; m < 8; ++m)
        #pragma unroll
        for (int n = 0; n < 4; ++n) acc[m][n] = (f32x4){0.f, 0.f, 0.f, 0.f};

    // prologue: t0ks0, t0ks1, t1ks0  (12 gloads; t0ks0's 4 oldest -> vmcnt(8))
    issue2(A, 0,  rb(0, 0, 0)); issue2(B, 0,  rb(0, 0, 1));
    issue2(A, 32, rb(0, 1, 0)); issue2(B, 32, rb(0, 1, 1));
    issue2(A, 64, rb(1, 0, 0)); issue2(B, 64, rb(1, 0, 1));
    asm volatile("s_waitcnt vmcnt(8)\n\ts_barrier" ::: "memory");
    __builtin_amdgcn_sched_barrier(0);

    bf16x8 af[4], bf[4];
    #pragma unroll
    for (int kt = 0; kt < 8; ++kt) {
        const int st = kt & 1;
        // ---- phase a ----
        if (kt + 1 < 8) issue2(A, (kt + 1) * 64 + 32, rb(st ^ 1, 1, 0));
        #pragma unroll
        for (int r = 0; r < 4; ++r)
            af[r] = *(const bf16x8*)(LDS + rb(st, 0, 0) + (wr * 8 + r) * 512 + lane * 8);
        #pragma unroll
        for (int n = 0; n < 4; ++n)
            bf[n] = *(const bf16x8*)(LDS + rb(st, 0, 1) + (wc * 4 + n) * 512 + lane * 8);
        asm volatile("s_waitcnt lgkmcnt(0)" ::: "memory");
        __builtin_amdgcn_sched_barrier(0);
        __builtin_amdgcn_s_setprio(1);
        #pragma unroll
        for (int r = 0; r < 4; ++r)
            #pragma unroll
            for (int n = 0; n < 4; ++n)
                acc[r][n] = __builtin_amdgcn_mfma_f32_16x16x32_bf16(af[r], bf[n], acc[r][n], 0, 0, 0);
        __builtin_amdgcn_s_setprio(0);
        // ---- phase b ----
        if (kt + 1 < 8) issue2(B, (kt + 1) * 64 + 32, rb(st ^ 1, 1, 1));
        #pragma unroll
        for (int r = 0; r < 4; ++r)
            af[r] = *(const bf16x8*)(LDS + rb(st, 0, 0) + (wr * 8 + 4 + r) * 512 + lane * 8);
        asm volatile("s_waitcnt lgkmcnt(0)" ::: "memory");
        __builtin_amdgcn_sched_barrier(0);
        __builtin_amdgcn_s_setprio(1);
        #pragma unroll
        for (int r = 0; r < 4; ++r)
            #pragma unroll
            for (int n = 0; n < 4; ++n)
                acc[4 + r][n] = __builtin_amdgcn_mfma_f32_16x16x32_bf16(af[r], bf[n], acc[4 + r][n], 0, 0, 0);
        __builtin_amdgcn_s_setprio(0);
        // ---- B1 ----
        if (kt <= 6) asm volatile("s_waitcnt vmcnt(8)\n\ts_barrier" ::: "memory");
        else         asm volatile("s_waitcnt vmcnt(0)\n\ts_barrier" ::: "memory");
        __builtin_amdgcn_sched_barrier(0);
        // ---- phase c ----
        if (kt + 2 < 8) issue2(A, (kt + 2) * 64, rb(st, 0, 0));
        #pragma unroll
        for (int r = 0; r < 4; ++r)
            af[r] = *(const bf16x8*)(LDS + rb(st, 1, 0) + (wr * 8 + r) * 512 + lane * 8);
        #pragma unroll
        for (int n = 0; n < 4; ++n)
            bf[n] = *(const bf16x8*)(LDS + rb(st, 1, 1) + (wc * 4 + n) * 512 + lane * 8);
        asm volatile("s_waitcnt lgkmcnt(0)" ::: "memory");
        __builtin_amdgcn_sched_barrier(0);
        __builtin_amdgcn_s_setprio(1);
        #pragma unroll
        for (int r = 0; r < 4; ++r)
            #pragma unroll
            for (int n = 0; n < 4; ++n)
                acc[r][n] = __builtin_amdgcn_mfma_f32_16x16x32_bf16(af[r], bf[n], acc[r][n], 0, 0, 0);
        __builtin_amdgcn_s_setprio(0);
        // ---- phase d ----
        if (kt + 2 < 8) issue2(B, (kt + 2) * 64, rb(st, 0, 1));
        #pragma unroll
        for (int r = 0; r < 4; ++r)
            af[r] = *(const bf16x8*)(LDS + rb(st, 1, 0) + (wr * 8 + 4 + r) * 512 + lane * 8);
        asm volatile("s_waitcnt lgkmcnt(0)" ::: "memory");
        __builtin_amdgcn_sched_barrier(0);
        __builtin_amdgcn_s_setprio(1);
        #pragma unroll
        for (int r = 0; r < 4; ++r)
            #pragma unroll
            for (int n = 0; n < 4; ++n)
                acc[4 + r][n] = __builtin_amdgcn_mfma_f32_16x16x32_bf16(af[r], bf[n], acc[4 + r][n], 0, 0, 0);
        __builtin_amdgcn_s_setprio(0);
        // ---- B2 ----
        if (kt < 7) {
            if (kt < 6) asm volatile("s_waitcnt vmcnt(8)\n\ts_barrier" ::: "memory");
            else        asm volatile("s_waitcnt vmcnt(4)\n\ts_barrier" ::: "memory");
            __builtin_amdgcn_sched_barrier(0);
        }
    }

    // ---- epilogue: exp over (j>i) pairs, both stat-sides ----
    int labj[4]; float muj[4], isj[4];
    #pragma unroll
    for (int n = 0; n < 4; ++n) {
        const int j = C0 + wc * 64 + n * 16 + f_l;
        labj[n] = labels[j]; muj[n] = mu_d[j]; isj[n] = inv2s2[j];
    }
    float local = 0.f;
    #pragma unroll
    for (int m = 0; m < 8; ++m) {
        const int ib = R0 + wr * 128 + m * 16 + q_l * 4;
        #pragma unroll
        for (int u = 0; u < 4; ++u) {
            const int   i  = ib + u;
            const int   li = labels[i];
            const float mi = mu_d[i];
            const float vi = inv2s2[i];
            #pragma unroll
            for (int n = 0; n < 4; ++n) {
                const int j = C0 + wc * 64 + n * 16 + f_l;
                const float s  = acc[m][n][u];
                const float d  = 1.0f - s;
                const float dj = d - muj[n];
                const float di = d - mi;
                const float e = __expf(s * TEMP_INV + dj * dj * isj[n])
                              + __expf(s * TEMP_INV + di * di * vi);
                local += (j > i && li != labj[n]) ? e : 0.f;
            }
        }
    }
    #pragma unroll
    for (int off = 1; off < 64; off <<= 1) local += __shfl_xor(local, off);
    asm volatile("s_waitcnt vmcnt(0) lgkmcnt(0)" ::: "memory");
    __syncthreads();
    float* redbuf = (float*)LDS;
    if (lane == 0) redbuf[w] = local;
    __syncthreads();
    if (tid == 0) {
        float s8 = 0.f;
        #pragma unroll
        for (int k = 0; k < 8; ++k) s8 += redbuf[k];
        atomicAdd(neg_acc, (double)s8);
    }
}

// ---------------- final loss ----------------
__global__ void loss_k(const double* __restrict__ accs, float* __restrict__ out)
{
    const double neg = accs[0], pos = accs[1];
    out[0] = (float)(-log(pos / (pos + neg)));
}

extern "C" void kernel_launch(void* const* d_in, const int* in_sizes, int n_in,
                              void* d_out, int out_size, void* d_ws, size_t ws_size,
                              hipStream_t stream)
{
    const float* z      = (const float*)d_in[0];
    const int*   labels = (const int*)d_in[1];
    float* out = (float*)d_out;

    char* ws = (char*)d_ws;
    __hip_bfloat16* zn  = (__hip_bfloat16*)ws;                        // 8 MiB
    __hip_bfloat16* znT = (__hip_bfloat16*)(ws + ((size_t)8 << 20));  // 8 MiB
    float* Gpart        = (float*)(ws + ((size_t)16 << 20));          // 32 MiB
    char* tail          = ws + ((size_t)48 << 20);
    float*  S        = (float*)tail;                                  // 512 f
    double* accs     = (double*)(S + 512);                            // [0]=neg [1]=pos
    float*  rsq_part = (float*)(accs + 2);                            // 16 x 8192 f
    float*  mu_d     = rsq_part + 16 * NTOT;                          // 8192 f
    float*  inv2s2   = mu_d + NTOT;                                   // 8192 f
    __hip_bfloat16* G1 = (__hip_bfloat16*)(inv2s2 + NTOT);            // 512 KiB

    (void)hipMemsetAsync(S, 0, 512 * sizeof(float) + 2 * sizeof(double), stream);

    normalize_k<<<NTOT / 4, 256, 0, stream>>>(z, zn);
    transpose_colsum_k<<<1024, 256, 0, stream>>>(zn, znT, S);
    gram_k<<<16 * GCH, 256, 0, stream>>>(znT, Gpart);
    gram_fin_k<<<512, 256, 0, stream>>>(Gpart, G1);
    rowstats_k<<<512, 256, 0, stream>>>(zn, G1, rsq_part);
    finalize_pos_k<<<NTOT / 4, 256, 0, stream>>>(zn, S, rsq_part, labels, mu_d, inv2s2, accs + 1);
    sim_neg_k<<<NBLK2, 512, 131072, stream>>>(zn, labels, mu_d, inv2s2, accs);
    loss_k<<<1, 1, 0, stream>>>(accs, out);
}